// Round 10
// baseline (226.199 us; speedup 1.0000x reference)
//
#include <hip/hip_runtime.h>
#include <hip/hip_bf16.h>
#include <stdint.h>

// ---------------------------------------------------------------------------
// Self-attention, single head, d=1024, seq=2048, batch=4, fp32 in/out.
// R17: triple-buffered staging for the NI=2 kernels (gemm_v, gemm_pv).
//      R8/R10/R12/R16 all ~930 TF/block across four schedules -> lockstep
//      is not the constraint. m218's lesson: the 8-phase gain IS the deep
//      counted vmcnt (loads issued >=2 K-steps before their gate); all my
//      gates waited on loads issued ~1 tile earlier (~issue-to-gate 1800-
//      2800 cyc vs L2-miss-under-load latency 900-2000+) -> partial stall
//      every tile ("serial sum" signature). Fix where LDS allows (NI=2):
//      3 buffers (A 3x32K + B 3x16K = 144KB), stage t+2 during tile t,
//      gate vmcnt(6) keeps t+2's 6 loads in flight, waits only t+1 (issued
//      2 tiles ago). qk/sexp (NI=4, would need 192KB) stay on the R16 path
//      -> pv/v are a clean A/B test of the latency theory.
//      Buffer audit: stage(t+2) -> buf (t+2)%3 last read by tile t-1 whose
//      reads completed before its end barrier; per-wave gate precedes the
//      tile-end barrier so tile t+1's data is published to all waves.
//      Register dataflow = R16 verified (afc: ph0->ph2, afn: ph1->ph3).
// Pipeline: cast_all | QK proj | V proj (-> Vt scatter) |
//           S = exp(QK^T) + rowsum partials | O = (P Vt^T)/rowsum
// Workspace (102 MiB): xb @ 0 (16; 1st MiB reused as part after v)
//   wcat @ 16 (6)  Q @ 22 (16)  K @ 38 (16)  Vt @ 54 (16)  S @ 70 (32)
// ---------------------------------------------------------------------------

typedef __attribute__((ext_vector_type(8))) short bf16x8;   // 8 bf16 = 4 VGPRs
typedef __attribute__((ext_vector_type(4))) float f32x4;

__device__ __forceinline__ void async_copy16(const void* g, void* l) {
  __builtin_amdgcn_global_load_lds(
      (__attribute__((address_space(1))) void*)(g),
      (__attribute__((address_space(3))) void*)(l),
      16, 0, 0);
}

#define SB0 __builtin_amdgcn_sched_barrier(0)

// ---- 256xBN / BK=64 / 1-barrier-per-tile double-buffered mainloop ----
// (R16 verified; used by qk/sexp with NI=4.)
template<int NI, int NT, int KS>
__device__ __forceinline__ void mainloop256(
    const __hip_bfloat16* __restrict__ aS,
    const __hip_bfloat16* __restrict__ bS,
    __hip_bfloat16* As, __hip_bfloat16* Bs,
    const int wid, const int wm, const int wn,
    const int l16, const int quad, const int sw,
    f32x4 (&acc)[8][NI])
{
  const bf16x8* Av = (const bf16x8*)As;
  const bf16x8* Bv = (const bf16x8*)Bs;
  char* lA = (char*)As + wid * 1024;     // wave-uniform stage base
  char* lB = (char*)Bs + wid * 1024;
  bf16x8 bfr[NI][2];
  bf16x8 afc[2][2], afn[2][2];

#define STG_A2(t) do { \
    _Pragma("unroll") \
    for (int p = 0; p < 4; ++p) \
      async_copy16(aS + ((t)*64 + (long long)p * 64 * KS), \
                   lA + ((t)&1)*32768 + p * 64 * 128); \
  } while (0)
#define STG_B2(t) do { \
    _Pragma("unroll") \
    for (int p = 0; p < NI; ++p) \
      async_copy16(bS + ((t)*64 + (long long)p * 64 * KS), \
                   lB + ((t)&1)*(NI*8192) + p * 64 * 128); \
  } while (0)
#define RD_AF(dst, t, phi) do { \
    _Pragma("unroll") \
    for (int m2 = 0; m2 < 2; ++m2) \
      _Pragma("unroll") \
      for (int kk = 0; kk < 2; ++kk) \
        dst[m2][kk] = Av[((t)&1)*2048 + (wm + ((phi)*2 + m2)*16 + l16)*8 + ((kk*4 + quad) ^ sw)]; \
  } while (0)
#define RD_BF(t, nlo, nhi) do { \
    _Pragma("unroll") \
    for (int ni = (nlo); ni < (nhi); ++ni) \
      _Pragma("unroll") \
      for (int kk = 0; kk < 2; ++kk) \
        bfr[ni][kk] = Bv[((t)&1)*(NI*512) + (wn + ni*16 + l16)*8 + ((kk*4 + quad) ^ sw)]; \
  } while (0)
#define MM(src, phi, nlo, nhi) do { \
    _Pragma("unroll") \
    for (int kk = 0; kk < 2; ++kk) \
      _Pragma("unroll") \
      for (int m2 = 0; m2 < 2; ++m2) \
        _Pragma("unroll") \
        for (int ni = (nlo); ni < (nhi); ++ni) \
          acc[(phi)*2 + m2][ni] = __builtin_amdgcn_mfma_f32_16x16x32_bf16( \
              src[m2][kk], bfr[ni][kk], acc[(phi)*2 + m2][ni], 0, 0, 0); \
  } while (0)
#define GATE0 do { SB0; \
    asm volatile("s_waitcnt vmcnt(0)" ::: "memory"); } while (0)
#define GNONE (void)0

#define TILE(t, STG_STMT, GATE_STMT) do { \
    RD_BF(t, 0, NI); \
    RD_AF(afc, t, 0); \
    RD_AF(afn, t, 1); \
    STG_STMT; \
    __builtin_amdgcn_s_setprio(1); MM(afc, 0, 0, NI); __builtin_amdgcn_s_setprio(0); \
    RD_AF(afc, t, 2); \
    __builtin_amdgcn_s_setprio(1); \
    MM(afn, 1, 0, NI); \
    __builtin_amdgcn_s_setprio(0); \
    RD_AF(afn, t, 3); \
    __builtin_amdgcn_s_setprio(1); \
    MM(afc, 2, 0, NI); \
    MM(afn, 3, 0, NI); \
    __builtin_amdgcn_s_setprio(0); \
    GATE_STMT; \
    SB0; \
    __builtin_amdgcn_s_barrier(); \
  } while (0)

  STG_B2(0); STG_A2(0);
  GATE0;
  __builtin_amdgcn_s_barrier();

  #pragma unroll 1
  for (int i = 0; i < NT / 2 - 1; ++i) {
    const int ta = 2 * i, tb = 2 * i + 1;
    TILE(ta, { STG_A2(ta + 1); STG_B2(ta + 1); }, GATE0);
    TILE(tb, { STG_A2(tb + 1); STG_B2(tb + 1); }, GATE0);
  }
  TILE(NT - 2, { STG_A2(NT - 1); STG_B2(NT - 1); }, GATE0);
  TILE(NT - 1, GNONE, GNONE);

#undef TILE
#undef GATE0
#undef GNONE
#undef MM
#undef RD_BF
#undef RD_AF
#undef STG_A2
#undef STG_B2
}

// ---- 256x128 / BK=64 / TRIPLE-buffered 1-barrier mainloop (NI=2) ----
// As: LDS [3][256*64] (96KB). Bs: LDS [3][128*64] (48KB).
// Stage t+2 during tile t; gate vmcnt(6) leaves t+2's 6 loads in flight.
template<int NT, int KS>
__device__ __forceinline__ void mainloop128tb(
    const __hip_bfloat16* __restrict__ aS,
    const __hip_bfloat16* __restrict__ bS,
    __hip_bfloat16* As, __hip_bfloat16* Bs,
    const int wid, const int wm, const int wn,
    const int l16, const int quad, const int sw,
    f32x4 (&acc)[8][2])
{
  const bf16x8* Av = (const bf16x8*)As;
  const bf16x8* Bv = (const bf16x8*)Bs;
  char* lA = (char*)As + wid * 1024;
  char* lB = (char*)Bs + wid * 1024;
  bf16x8 bfr[2][2];
  bf16x8 afc[2][2], afn[2][2];

#define STG_A3(t, bw) do { \
    _Pragma("unroll") \
    for (int p = 0; p < 4; ++p) \
      async_copy16(aS + ((t)*64 + (long long)p * 64 * KS), \
                   lA + (bw)*32768 + p * 64 * 128); \
  } while (0)
#define STG_B3(t, bw) do { \
    _Pragma("unroll") \
    for (int p = 0; p < 2; ++p) \
      async_copy16(bS + ((t)*64 + (long long)p * 64 * KS), \
                   lB + (bw)*16384 + p * 64 * 128); \
  } while (0)
#define RD_AF3(dst, br, phi) do { \
    _Pragma("unroll") \
    for (int m2 = 0; m2 < 2; ++m2) \
      _Pragma("unroll") \
      for (int kk = 0; kk < 2; ++kk) \
        dst[m2][kk] = Av[(br)*2048 + (wm + ((phi)*2 + m2)*16 + l16)*8 + ((kk*4 + quad) ^ sw)]; \
  } while (0)
#define RD_BF3(br) do { \
    _Pragma("unroll") \
    for (int ni = 0; ni < 2; ++ni) \
      _Pragma("unroll") \
      for (int kk = 0; kk < 2; ++kk) \
        bfr[ni][kk] = Bv[(br)*1024 + (wn + ni*16 + l16)*8 + ((kk*4 + quad) ^ sw)]; \
  } while (0)
#define MM3(src, phi) do { \
    _Pragma("unroll") \
    for (int kk = 0; kk < 2; ++kk) \
      _Pragma("unroll") \
      for (int m2 = 0; m2 < 2; ++m2) \
        _Pragma("unroll") \
        for (int ni = 0; ni < 2; ++ni) \
          acc[(phi)*2 + m2][ni] = __builtin_amdgcn_mfma_f32_16x16x32_bf16( \
              src[m2][kk], bfr[ni][kk], acc[(phi)*2 + m2][ni], 0, 0, 0); \
  } while (0)
#define GATE6 do { SB0; \
    asm volatile("s_waitcnt vmcnt(6)" ::: "memory"); } while (0)
#define GATE0T do { SB0; \
    asm volatile("s_waitcnt vmcnt(0)" ::: "memory"); } while (0)
#define GNONE3 (void)0

#define TILE3(t, br, STG_STMT, GATE_STMT) do { \
    RD_BF3(br); \
    RD_AF3(afc, br, 0); \
    RD_AF3(afn, br, 1); \
    STG_STMT; \
    __builtin_amdgcn_s_setprio(1); MM3(afc, 0); __builtin_amdgcn_s_setprio(0); \
    RD_AF3(afc, br, 2); \
    __builtin_amdgcn_s_setprio(1); MM3(afn, 1); __builtin_amdgcn_s_setprio(0); \
    RD_AF3(afn, br, 3); \
    __builtin_amdgcn_s_setprio(1); MM3(afc, 2); MM3(afn, 3); __builtin_amdgcn_s_setprio(0); \
    GATE_STMT; \
    SB0; \
    __builtin_amdgcn_s_barrier(); \
  } while (0)

  // prologue: stage tiles 0 and 1; wait tile 0 (keep tile 1's 6 in flight)
  STG_B3(0, 0); STG_A3(0, 0); STG_B3(1, 1); STG_A3(1, 1);
  GATE6;
  __builtin_amdgcn_s_barrier();

  int br = 0;
  #pragma unroll 1
  for (int t = 0; t < NT - 2; ++t) {
    const int bw = (br + 2 >= 3) ? (br - 1) : (br + 2);   // (t+2)%3
    TILE3(t, br, { STG_A3(t + 2, bw); STG_B3(t + 2, bw); }, GATE6);
    br = (br + 1 == 3) ? 0 : (br + 1);
  }
  TILE3(NT - 2, br, GNONE3, GATE0T);
  br = (br + 1 == 3) ? 0 : (br + 1);
  TILE3(NT - 1, br, GNONE3, GNONE3);

#undef TILE3
#undef GATE6
#undef GATE0T
#undef GNONE3
#undef MM3
#undef RD_BF3
#undef RD_AF3
#undef STG_A3
#undef STG_B3
}

// ---------------- Q,K projection, 256x256, grid 256 ----------------
// A = xb [8192,1024], B = wcat rows 0..2047 (Wq | Wk)
__global__ __launch_bounds__(512, 2)
void gemm_qk(const __hip_bfloat16* __restrict__ A,
             const __hip_bfloat16* __restrict__ B,
             __hip_bfloat16* __restrict__ Q,
             __hip_bfloat16* __restrict__ Kk)
{
  __shared__ __align__(16) __hip_bfloat16 As[2][256 * 64];   // 64 KB
  __shared__ __align__(16) __hip_bfloat16 Bs[2][256 * 64];   // 64 KB

  // XCD-chunked bijective swizzle: 256 = 8 XCD * 32.
  const int bid = blockIdx.x;
  const int s   = (bid & 7) * 32 + (bid >> 3);
  const long long tile_m = (long long)(s >> 3) * 256;
  const long long tile_n = (long long)(s & 7) * 256;

  const int tid  = threadIdx.x;
  const int wid  = tid >> 6;
  const int lane = tid & 63;
  const int srow = wid * 8 + (lane >> 3);
  const int scol = ((lane & 7) ^ (lane >> 3)) * 8;   // swizzled source chunk

  const __hip_bfloat16* aS = A + (tile_m + srow) * 1024 + scol;
  const __hip_bfloat16* bS = B + (tile_n + srow) * 1024 + scol;

  const int wm   = (wid >> 2) * 128;
  const int wn   = (wid & 3) * 64;
  const int quad = lane >> 4;
  const int l16  = lane & 15;
  const int sw   = l16 & 7;

  f32x4 acc[8][4];
  #pragma unroll
  for (int mi = 0; mi < 8; ++mi)
    #pragma unroll
    for (int ni = 0; ni < 4; ++ni)
      acc[mi][ni] = (f32x4){0.f, 0.f, 0.f, 0.f};

  mainloop256<4, 16, 1024>(aS, bS, &As[0][0], &Bs[0][0],
                           wid, wm, wn, l16, quad, sw, acc);

  // C/D layout (m89/m91): col = l16, row = quad*4 + r
  const int mat = (int)(tile_n >> 10);
  __hip_bfloat16* outp = (mat == 0) ? Q : Kk;
  const float scale = (mat == 0) ? 0.03125f : 1.0f;   // 1/sqrt(1024) in Q
  const int coln0 = (int)(tile_n & 1023);
  #pragma unroll
  for (int mi = 0; mi < 8; ++mi) {
    #pragma unroll
    for (int r = 0; r < 4; ++r) {
      const long long row = tile_m + wm + mi * 16 + quad * 4 + r;
      #pragma unroll
      for (int ni = 0; ni < 4; ++ni) {
        const int col = coln0 + wn + ni * 16 + l16;
        outp[row * 1024 + col] = __float2bfloat16(acc[mi][ni][r] * scale);
      }
    }
  }
}

// ---------------- V projection, 256x128, grid 256, triple-buffered ----------------
// A = xb [8192,1024], B = Wv rows.  V -> Vt [4][1024][2048] via 8B scatter.
__global__ __launch_bounds__(512, 2)
void gemm_v(const __hip_bfloat16* __restrict__ A,
            const __hip_bfloat16* __restrict__ B,
            __hip_bfloat16* __restrict__ Vt)
{
  __shared__ __align__(16) __hip_bfloat16 As[3][256 * 64];   // 96 KB
  __shared__ __align__(16) __hip_bfloat16 Bs[3][128 * 64];   // 48 KB

  const int bid = blockIdx.x;
  const int s   = (bid & 7) * 32 + (bid >> 3);
  const long long tile_m = (long long)(s >> 3) * 256;
  const long long tile_n = (long long)(s & 7) * 128;

  const int tid  = threadIdx.x;
  const int wid  = tid >> 6;
  const int lane = tid & 63;
  const int srow = wid * 8 + (lane >> 3);
  const int scol = ((lane & 7) ^ (lane >> 3)) * 8;

  const __hip_bfloat16* aS = A + (tile_m + srow) * 1024 + scol;
  const __hip_bfloat16* bS = B + (tile_n + srow) * 1024 + scol;

  const int wm   = (wid >> 2) * 128;
  const int wn   = (wid & 3) * 32;
  const int quad = lane >> 4;
  const int l16  = lane & 15;
  const int sw   = l16 & 7;

  f32x4 acc[8][2];
  #pragma unroll
  for (int mi = 0; mi < 8; ++mi)
    #pragma unroll
    for (int ni = 0; ni < 2; ++ni)
      acc[mi][ni] = (f32x4){0.f, 0.f, 0.f, 0.f};

  mainloop128tb<16, 1024>(aS, bS, &As[0][0], &Bs[0][0],
                          wid, wm, wn, l16, quad, sw, acc);

  // V: lane's 4 r-values are seq-consecutive -> one 8B store per (mi,ni).
  const int b    = (int)(tile_m >> 11);
  const int seq0 = (int)(tile_m & 2047);
  const int d0   = (int)tile_n;
  #pragma unroll
  for (int mi = 0; mi < 8; ++mi) {
    const int seq = seq0 + wm + mi * 16 + quad * 4;
    #pragma unroll
    for (int ni = 0; ni < 2; ++ni) {
      const int d = d0 + wn + ni * 16 + l16;
      union { ushort4 u; unsigned short sh[4]; } pk;
      #pragma unroll
      for (int r = 0; r < 4; ++r)
        pk.sh[r] = __bfloat16_as_ushort(__float2bfloat16(acc[mi][ni][r]));
      *(ushort4*)(Vt + ((long long)(b * 1024 + d)) * 2048 + seq) = pk.u;
    }
  }
}

// ---------------- S = exp(Q K^T) + row-sum partials, 256x256 ----------------
__global__ __launch_bounds__(512, 2)
void gemm_s_exp(const __hip_bfloat16* __restrict__ A,
                const __hip_bfloat16* __restrict__ B,
                __hip_bfloat16* __restrict__ Cout,
                float* __restrict__ part)
{
  __shared__ __align__(16) __hip_bfloat16 As[2][256 * 64];   // 64 KB
  __shared__ __align__(16) __hip_bfloat16 Bs[2][256 * 64];   // 64 KB

  // XCD swizzle: each XCD owns one batch-half: 4 tile_m x 8 tile_n.
  const int u   = blockIdx.x + (blockIdx.y << 3) + (blockIdx.z << 6);
  const int xcd = u & 7;
  const int rr  = u >> 3;                 // 0..31
  const int bz  = xcd >> 1;               // 2 XCDs per batch
  const int tmi = ((xcd & 1) << 2) + (rr >> 3);
  const int tni = rr & 7;

  A += (long long)bz * 2048 * 1024;
  B += (long long)bz * 2048 * 1024;

  const long long tile_m = (long long)tmi * 256;
  const long long tile_n = (long long)tni * 256;

  const int tid  = threadIdx.x;
  const int wid  = tid >> 6;
  const int lane = tid & 63;
  const int srow = wid * 8 + (lane >> 3);
  const int scol = ((lane & 7) ^ (lane >> 3)) * 8;

  const __hip_bfloat16* aS = A + (tile_m + srow) * 1024 + scol;
  const __hip_bfloat16* bS = B + (tile_n + srow) * 1024 + scol;

  const int wm   = (wid >> 2) * 128;
  const int wn   = (wid & 3) * 64;
  const int quad = lane >> 4;
  const int l16  = lane & 15;
  const int sw   = l16 & 7;

  f32x4 acc[8][4];
  #pragma unroll
  for (int mi = 0; mi < 8; ++mi)
    #pragma unroll
    for (int ni = 0; ni < 4; ++ni)
      acc[mi][ni] = (f32x4){0.f, 0.f, 0.f, 0.f};

  mainloop256<4, 16, 1024>(aS, bS, &As[0][0], &Bs[0][0],
                           wid, wm, wn, l16, quad, sw, acc);

  // epilogue: exp, bf16 store, per-wave 64-col row partials (32 per row total)
  __hip_bfloat16* C = Cout + (long long)bz * 2048 * 2048;
  #pragma unroll
  for (int mi = 0; mi < 8; ++mi) {
    #pragma unroll
    for (int r = 0; r < 4; ++r) {
      const long long row = tile_m + wm + mi * 16 + quad * 4 + r;
      float ssum = 0.f;
      #pragma unroll
      for (int ni = 0; ni < 4; ++ni) {
        const float e = __expf(acc[mi][ni][r]);
        const __hip_bfloat16 h = __float2bfloat16(e);
        C[row * 2048 + tile_n + wn + ni * 16 + l16] = h;
        ssum += __bfloat162float(h);
      }
      #pragma unroll
      for (int off = 1; off < 16; off <<= 1) ssum += __shfl_xor(ssum, off, 64);
      if (l16 == 0)
        part[((long long)bz * 2048 + row) * 32 + tni * 4 + (wid & 3)] = ssum;
    }
  }
}

// ---------------- O = (P Vt^T) / rowsum, 256x128, triple-buffered ----------------
__global__ __launch_bounds__(512, 2)
void gemm_pv(const __hip_bfloat16* __restrict__ A,     // expS [b][2048,2048]
             const __hip_bfloat16* __restrict__ B,     // Vt   [b][1024,2048]
             const float* __restrict__ part,           // [8192][32]
             float* __restrict__ Cout)                 // O    [b][2048,1024]
{
  __shared__ __align__(16) __hip_bfloat16 As[3][256 * 64];   // 96 KB
  __shared__ __align__(16) __hip_bfloat16 Bs[3][128 * 64];   // 48 KB
  __shared__ float rinv[256];

  // XCD swizzle: each XCD owns 4 tile_m x 8 tile_n of one batch.
  const int u   = blockIdx.x + (blockIdx.y << 3) + (blockIdx.z << 6);
  const int xcd = u & 7;
  const int rr  = u >> 3;
  const int bz  = xcd >> 1;
  const int tmi = ((xcd & 1) << 2) + (rr >> 3);
  const int tni = rr & 7;

  A += (long long)bz * 2048 * 2048;
  B += (long long)bz * 1024 * 2048;

  const long long tile_m = (long long)tmi * 256;
  const long long tile_n = (long long)tni * 128;

  const int tid  = threadIdx.x;
  const int wid  = tid >> 6;
  const int lane = tid & 63;
  const int srow = wid * 8 + (lane >> 3);
  const int scol = ((lane & 7) ^ (lane >> 3)) * 8;

  const __hip_bfloat16* aS = A + (tile_m + srow) * 2048 + scol;
  const __hip_bfloat16* bS = B + (tile_n + srow) * 2048 + scol;

  const int wm   = (wid >> 2) * 128;
  const int wn   = (wid & 3) * 32;
  const int quad = lane >> 4;
  const int l16  = lane & 15;
  const int sw   = l16 & 7;

  f32x4 acc[8][2];
  #pragma unroll
  for (int mi = 0; mi < 8; ++mi)
    #pragma unroll
    for (int ni = 0; ni < 2; ++ni)
      acc[mi][ni] = (f32x4){0.f, 0.f, 0.f, 0.f};

  mainloop128tb<32, 2048>(aS, bS, &As[0][0], &Bs[0][0],
                          wid, wm, wn, l16, quad, sw, acc);

  // gather this tile's 256 row-sums (32 partials each), store reciprocal
  if (tid < 256) {
    const float4* pp = (const float4*)(part + ((long long)bz * 2048 + tile_m + tid) * 32);
    float s = 0.f;
    #pragma unroll
    for (int j = 0; j < 8; ++j) {
      const float4 f = pp[j];
      s += f.x + f.y + f.z + f.w;
    }
    rinv[tid] = 1.f / s;
  }
  __syncthreads();

  float* C = Cout + (long long)bz * 2048 * 1024;
  #pragma unroll
  for (int mi = 0; mi < 8; ++mi) {
    #pragma unroll
    for (int r = 0; r < 4; ++r) {
      const int rloc = wm + mi * 16 + quad * 4 + r;
      const float inv = rinv[rloc];
      const long long row = tile_m + rloc;
      #pragma unroll
      for (int ni = 0; ni < 2; ++ni) {
        const long long col = tile_n + wn + ni * 16 + l16;
        C[row * 1024 + col] = acc[mi][ni][r] * inv;
      }
    }
  }
}

// ---------------- all casts in one dispatch ----------------
__global__ __launch_bounds__(256)
void cast_all(const float* __restrict__ x,
              const float* __restrict__ Wq, const float* __restrict__ Wk,
              const float* __restrict__ Wv,
              __hip_bfloat16* __restrict__ xb, __hip_bfloat16* __restrict__ wcat)
{
  const int bx = blockIdx.x;
  const float* src;
  __hip_bfloat16* dst;
  int i;
  if (bx < 8192) {                      // x: 2097152 float4s
    src = x; dst = xb; i = bx * 256 + threadIdx.x;
  } else {                              // weights: 262144 float4s each
    const int which = (bx - 8192) >> 10;
    src = (which == 0) ? Wq : (which == 1) ? Wk : Wv;
    dst = wcat + (long long)which * 1048576;
    i = ((bx - 8192) & 1023) * 256 + threadIdx.x;
  }
  const float4 f = ((const float4*)src)[i];
  union { ushort4 u; __hip_bfloat16 h[4]; } r;
  r.h[0] = __float2bfloat16(f.x);
  r.h[1] = __float2bfloat16(f.y);
  r.h[2] = __float2bfloat16(f.z);
  r.h[3] = __float2bfloat16(f.w);
  ((ushort4*)dst)[i] = r.u;
}

extern "C" void kernel_launch(void* const* d_in, const int* in_sizes, int n_in,
                              void* d_out, int out_size, void* d_ws, size_t ws_size,
                              hipStream_t stream)
{
  (void)in_sizes; (void)n_in; (void)out_size; (void)ws_size;

  const float* x  = (const float*)d_in[0];
  const float* Wq = (const float*)d_in[1];
  const float* Wk = (const float*)d_in[2];
  const float* Wv = (const float*)d_in[3];
  float* out = (float*)d_out;

  char* ws = (char*)d_ws;
  __hip_bfloat16* xb   = (__hip_bfloat16*)(ws);            // dead after gemm_v
  float*          part = (float*)(ws);                     // reuses xb region (1 MB)
  __hip_bfloat16* wcat = (__hip_bfloat16*)(ws + (16LL << 20));
  __hip_bfloat16* Q    = (__hip_bfloat16*)(ws + (22LL << 20));
  __hip_bfloat16* Kk   = (__hip_bfloat16*)(ws + (38LL << 20));
  __hip_bfloat16* Vt   = (__hip_bfloat16*)(ws + (54LL << 20));
  __hip_bfloat16* S    = (__hip_bfloat16*)(ws + (70LL << 20));

  cast_all<<<11264, 256, 0, stream>>>(x, Wq, Wk, Wv, xb, wcat);

  // Q,K projection: 32x8 tiles of 256^2 = 256 blocks (1 clean round)
  gemm_qk<<<256, 512, 0, stream>>>(xb, wcat, Q, Kk);

  // V projection: 32x8 tiles of 256x128 = 256 blocks; V lands transposed
  gemm_v<<<256, 512, 0, stream>>>(xb, wcat + 2097152, Vt);

  // S = exp(Q K^T), row-sum partials -> part (overwrites dead xb)
  gemm_s_exp<<<dim3(8, 8, 4), 512, 0, stream>>>(Q, Kk, S, part);

  // O = (P Vt^T) / rowsum -> fp32 d_out
  gemm_pv<<<dim3(8, 8, 4), 512, 0, stream>>>(S, Vt, part, out);
}

// Round 11
// 225.628 us; speedup vs baseline: 1.0025x; 1.0025x over previous
//
#include <hip/hip_runtime.h>
#include <hip/hip_bf16.h>
#include <stdint.h>

// ---------------------------------------------------------------------------
// Self-attention, single head, d=1024, seq=2048, batch=4, fp32 in/out.
// R18: revert R17 triple-buffer (regressed: 43.4->49.8 us). NI=2 kernels
//      (gemm_v, gemm_pv) get a FENCE-FREE full-prefetch mainloop:
//      all 20 fragment reads (af[8][2], bfr[2][2], static-indexed) issued
//      at tile top, NO setprio, no SB0 inside the tile. Rationale: every
//      variant since R8 bracketed MFMA clusters with s_setprio, whose
//      unmodeled side effects pin the schedule into {reads|fence|MFMA|
//      fence} bursts -> measured serial-sum timing (LDS ~1900 cyc + MFMA
//      ~1033 cyc per CU-tile vs max ~1900). Freeing the scheduler lets
//      reads stream under MFMAs (counted lgkm waits auto-inserted).
//      qk/sexp stay byte-identical R16 (control group for the A/B).
//      Hazards (audited, == R16): stage(t+1)->buf^1 last read before
//      t-1's end barrier; per-wave vmcnt(0) gate precedes end barrier;
//      af/bfr written once per tile, read after.
// Pipeline: cast_all | QK proj | V proj (-> Vt scatter) |
//           S = exp(QK^T) + rowsum partials | O = (P Vt^T)/rowsum
// Workspace (102 MiB): xb @ 0 (16; 1st MiB reused as part after v)
//   wcat @ 16 (6)  Q @ 22 (16)  K @ 38 (16)  Vt @ 54 (16)  S @ 70 (32)
// ---------------------------------------------------------------------------

typedef __attribute__((ext_vector_type(8))) short bf16x8;   // 8 bf16 = 4 VGPRs
typedef __attribute__((ext_vector_type(4))) float f32x4;

__device__ __forceinline__ void async_copy16(const void* g, void* l) {
  __builtin_amdgcn_global_load_lds(
      (__attribute__((address_space(1))) void*)(g),
      (__attribute__((address_space(3))) void*)(l),
      16, 0, 0);
}

#define SB0 __builtin_amdgcn_sched_barrier(0)

// ---- 256xBN / BK=64 / 1-barrier-per-tile double-buffered mainloop ----
// (R16 verified; used by qk/sexp with NI=4.)
template<int NI, int NT, int KS>
__device__ __forceinline__ void mainloop256(
    const __hip_bfloat16* __restrict__ aS,
    const __hip_bfloat16* __restrict__ bS,
    __hip_bfloat16* As, __hip_bfloat16* Bs,
    const int wid, const int wm, const int wn,
    const int l16, const int quad, const int sw,
    f32x4 (&acc)[8][NI])
{
  const bf16x8* Av = (const bf16x8*)As;
  const bf16x8* Bv = (const bf16x8*)Bs;
  char* lA = (char*)As + wid * 1024;     // wave-uniform stage base
  char* lB = (char*)Bs + wid * 1024;
  bf16x8 bfr[NI][2];
  bf16x8 afc[2][2], afn[2][2];

#define STG_A2(t) do { \
    _Pragma("unroll") \
    for (int p = 0; p < 4; ++p) \
      async_copy16(aS + ((t)*64 + (long long)p * 64 * KS), \
                   lA + ((t)&1)*32768 + p * 64 * 128); \
  } while (0)
#define STG_B2(t) do { \
    _Pragma("unroll") \
    for (int p = 0; p < NI; ++p) \
      async_copy16(bS + ((t)*64 + (long long)p * 64 * KS), \
                   lB + ((t)&1)*(NI*8192) + p * 64 * 128); \
  } while (0)
#define RD_AF(dst, t, phi) do { \
    _Pragma("unroll") \
    for (int m2 = 0; m2 < 2; ++m2) \
      _Pragma("unroll") \
      for (int kk = 0; kk < 2; ++kk) \
        dst[m2][kk] = Av[((t)&1)*2048 + (wm + ((phi)*2 + m2)*16 + l16)*8 + ((kk*4 + quad) ^ sw)]; \
  } while (0)
#define RD_BF(t, nlo, nhi) do { \
    _Pragma("unroll") \
    for (int ni = (nlo); ni < (nhi); ++ni) \
      _Pragma("unroll") \
      for (int kk = 0; kk < 2; ++kk) \
        bfr[ni][kk] = Bv[((t)&1)*(NI*512) + (wn + ni*16 + l16)*8 + ((kk*4 + quad) ^ sw)]; \
  } while (0)
#define MM(src, phi, nlo, nhi) do { \
    _Pragma("unroll") \
    for (int kk = 0; kk < 2; ++kk) \
      _Pragma("unroll") \
      for (int m2 = 0; m2 < 2; ++m2) \
        _Pragma("unroll") \
        for (int ni = (nlo); ni < (nhi); ++ni) \
          acc[(phi)*2 + m2][ni] = __builtin_amdgcn_mfma_f32_16x16x32_bf16( \
              src[m2][kk], bfr[ni][kk], acc[(phi)*2 + m2][ni], 0, 0, 0); \
  } while (0)
#define GATE0 do { SB0; \
    asm volatile("s_waitcnt vmcnt(0)" ::: "memory"); } while (0)
#define GNONE (void)0

#define TILE(t, STG_STMT, GATE_STMT) do { \
    RD_BF(t, 0, NI); \
    RD_AF(afc, t, 0); \
    RD_AF(afn, t, 1); \
    STG_STMT; \
    __builtin_amdgcn_s_setprio(1); MM(afc, 0, 0, NI); __builtin_amdgcn_s_setprio(0); \
    RD_AF(afc, t, 2); \
    __builtin_amdgcn_s_setprio(1); \
    MM(afn, 1, 0, NI); \
    __builtin_amdgcn_s_setprio(0); \
    RD_AF(afn, t, 3); \
    __builtin_amdgcn_s_setprio(1); \
    MM(afc, 2, 0, NI); \
    MM(afn, 3, 0, NI); \
    __builtin_amdgcn_s_setprio(0); \
    GATE_STMT; \
    SB0; \
    __builtin_amdgcn_s_barrier(); \
  } while (0)

  STG_B2(0); STG_A2(0);
  GATE0;
  __builtin_amdgcn_s_barrier();

  #pragma unroll 1
  for (int i = 0; i < NT / 2 - 1; ++i) {
    const int ta = 2 * i, tb = 2 * i + 1;
    TILE(ta, { STG_A2(ta + 1); STG_B2(ta + 1); }, GATE0);
    TILE(tb, { STG_A2(tb + 1); STG_B2(tb + 1); }, GATE0);
  }
  TILE(NT - 2, { STG_A2(NT - 1); STG_B2(NT - 1); }, GATE0);
  TILE(NT - 1, GNONE, GNONE);

#undef TILE
#undef GATE0
#undef GNONE
#undef MM
#undef RD_BF
#undef RD_AF
#undef STG_A2
#undef STG_B2
}

// ---- 256x128 / BK=64 / fence-free full-prefetch mainloop (NI=2) ----
// As: LDS [2][256*64] (64KB). Bs: LDS [2][128*64] (32KB).
// All 20 fragment reads at tile top into af[8][2]/bfr[2][2]; no setprio,
// no sched_barrier inside the tile; compiler schedules reads under MFMAs.
template<int NT, int KS>
__device__ __forceinline__ void mainloop128pf(
    const __hip_bfloat16* __restrict__ aS,
    const __hip_bfloat16* __restrict__ bS,
    __hip_bfloat16* As, __hip_bfloat16* Bs,
    const int wid, const int wm, const int wn,
    const int l16, const int quad, const int sw,
    f32x4 (&acc)[8][2])
{
  const bf16x8* Av = (const bf16x8*)As;
  const bf16x8* Bv = (const bf16x8*)Bs;
  char* lA = (char*)As + wid * 1024;
  char* lB = (char*)Bs + wid * 1024;
  bf16x8 af[8][2];     // 64 VGPR, static-indexed (full unroll)
  bf16x8 bfr[2][2];    // 16 VGPR

#define STG_A2(t) do { \
    _Pragma("unroll") \
    for (int p = 0; p < 4; ++p) \
      async_copy16(aS + ((t)*64 + (long long)p * 64 * KS), \
                   lA + ((t)&1)*32768 + p * 64 * 128); \
  } while (0)
#define STG_B2(t) do { \
    _Pragma("unroll") \
    for (int p = 0; p < 2; ++p) \
      async_copy16(bS + ((t)*64 + (long long)p * 64 * KS), \
                   lB + ((t)&1)*16384 + p * 64 * 128); \
  } while (0)
#define GATE0 do { SB0; \
    asm volatile("s_waitcnt vmcnt(0)" ::: "memory"); } while (0)
#define GNONE (void)0

#define TILEPF(t, STG_STMT, GATE_STMT) do { \
    _Pragma("unroll") \
    for (int m = 0; m < 8; ++m) \
      _Pragma("unroll") \
      for (int kk = 0; kk < 2; ++kk) \
        af[m][kk] = Av[((t)&1)*2048 + (wm + m*16 + l16)*8 + ((kk*4 + quad) ^ sw)]; \
    _Pragma("unroll") \
    for (int ni = 0; ni < 2; ++ni) \
      _Pragma("unroll") \
      for (int kk = 0; kk < 2; ++kk) \
        bfr[ni][kk] = Bv[((t)&1)*1024 + (wn + ni*16 + l16)*8 + ((kk*4 + quad) ^ sw)]; \
    STG_STMT; \
    _Pragma("unroll") \
    for (int kk = 0; kk < 2; ++kk) \
      _Pragma("unroll") \
      for (int m = 0; m < 8; ++m) \
        _Pragma("unroll") \
        for (int ni = 0; ni < 2; ++ni) \
          acc[m][ni] = __builtin_amdgcn_mfma_f32_16x16x32_bf16( \
              af[m][kk], bfr[ni][kk], acc[m][ni], 0, 0, 0); \
    GATE_STMT; \
    SB0; \
    __builtin_amdgcn_s_barrier(); \
  } while (0)

  STG_B2(0); STG_A2(0);
  GATE0;
  __builtin_amdgcn_s_barrier();

  #pragma unroll 1
  for (int i = 0; i < NT / 2 - 1; ++i) {
    const int ta = 2 * i, tb = 2 * i + 1;
    TILEPF(ta, { STG_A2(ta + 1); STG_B2(ta + 1); }, GATE0);
    TILEPF(tb, { STG_A2(tb + 1); STG_B2(tb + 1); }, GATE0);
  }
  TILEPF(NT - 2, { STG_A2(NT - 1); STG_B2(NT - 1); }, GATE0);
  TILEPF(NT - 1, GNONE, GNONE);

#undef TILEPF
#undef GATE0
#undef GNONE
#undef STG_A2
#undef STG_B2
}

// ---------------- Q,K projection, 256x256, grid 256 ----------------
// A = xb [8192,1024], B = wcat rows 0..2047 (Wq | Wk)
__global__ __launch_bounds__(512, 2)
void gemm_qk(const __hip_bfloat16* __restrict__ A,
             const __hip_bfloat16* __restrict__ B,
             __hip_bfloat16* __restrict__ Q,
             __hip_bfloat16* __restrict__ Kk)
{
  __shared__ __align__(16) __hip_bfloat16 As[2][256 * 64];   // 64 KB
  __shared__ __align__(16) __hip_bfloat16 Bs[2][256 * 64];   // 64 KB

  // XCD-chunked bijective swizzle: 256 = 8 XCD * 32.
  const int bid = blockIdx.x;
  const int s   = (bid & 7) * 32 + (bid >> 3);
  const long long tile_m = (long long)(s >> 3) * 256;
  const long long tile_n = (long long)(s & 7) * 256;

  const int tid  = threadIdx.x;
  const int wid  = tid >> 6;
  const int lane = tid & 63;
  const int srow = wid * 8 + (lane >> 3);
  const int scol = ((lane & 7) ^ (lane >> 3)) * 8;   // swizzled source chunk

  const __hip_bfloat16* aS = A + (tile_m + srow) * 1024 + scol;
  const __hip_bfloat16* bS = B + (tile_n + srow) * 1024 + scol;

  const int wm   = (wid >> 2) * 128;
  const int wn   = (wid & 3) * 64;
  const int quad = lane >> 4;
  const int l16  = lane & 15;
  const int sw   = l16 & 7;

  f32x4 acc[8][4];
  #pragma unroll
  for (int mi = 0; mi < 8; ++mi)
    #pragma unroll
    for (int ni = 0; ni < 4; ++ni)
      acc[mi][ni] = (f32x4){0.f, 0.f, 0.f, 0.f};

  mainloop256<4, 16, 1024>(aS, bS, &As[0][0], &Bs[0][0],
                           wid, wm, wn, l16, quad, sw, acc);

  // C/D layout (m89/m91): col = l16, row = quad*4 + r
  const int mat = (int)(tile_n >> 10);
  __hip_bfloat16* outp = (mat == 0) ? Q : Kk;
  const float scale = (mat == 0) ? 0.03125f : 1.0f;   // 1/sqrt(1024) in Q
  const int coln0 = (int)(tile_n & 1023);
  #pragma unroll
  for (int mi = 0; mi < 8; ++mi) {
    #pragma unroll
    for (int r = 0; r < 4; ++r) {
      const long long row = tile_m + wm + mi * 16 + quad * 4 + r;
      #pragma unroll
      for (int ni = 0; ni < 4; ++ni) {
        const int col = coln0 + wn + ni * 16 + l16;
        outp[row * 1024 + col] = __float2bfloat16(acc[mi][ni][r] * scale);
      }
    }
  }
}

// ---------------- V projection, 256x128, grid 256, fence-free ----------------
// A = xb [8192,1024], B = Wv rows.  V -> Vt [4][1024][2048] via 8B scatter.
__global__ __launch_bounds__(512, 2)
void gemm_v(const __hip_bfloat16* __restrict__ A,
            const __hip_bfloat16* __restrict__ B,
            __hip_bfloat16* __restrict__ Vt)
{
  __shared__ __align__(16) __hip_bfloat16 As[2][256 * 64];   // 64 KB
  __shared__ __align__(16) __hip_bfloat16 Bs[2][128 * 64];   // 32 KB

  const int bid = blockIdx.x;
  const int s   = (bid & 7) * 32 + (bid >> 3);
  const long long tile_m = (long long)(s >> 3) * 256;
  const long long tile_n = (long long)(s & 7) * 128;

  const int tid  = threadIdx.x;
  const int wid  = tid >> 6;
  const int lane = tid & 63;
  const int srow = wid * 8 + (lane >> 3);
  const int scol = ((lane & 7) ^ (lane >> 3)) * 8;

  const __hip_bfloat16* aS = A + (tile_m + srow) * 1024 + scol;
  const __hip_bfloat16* bS = B + (tile_n + srow) * 1024 + scol;

  const int wm   = (wid >> 2) * 128;
  const int wn   = (wid & 3) * 32;
  const int quad = lane >> 4;
  const int l16  = lane & 15;
  const int sw   = l16 & 7;

  f32x4 acc[8][2];
  #pragma unroll
  for (int mi = 0; mi < 8; ++mi)
    #pragma unroll
    for (int ni = 0; ni < 2; ++ni)
      acc[mi][ni] = (f32x4){0.f, 0.f, 0.f, 0.f};

  mainloop128pf<16, 1024>(aS, bS, &As[0][0], &Bs[0][0],
                          wid, wm, wn, l16, quad, sw, acc);

  // V: lane's 4 r-values are seq-consecutive -> one 8B store per (mi,ni).
  const int b    = (int)(tile_m >> 11);
  const int seq0 = (int)(tile_m & 2047);
  const int d0   = (int)tile_n;
  #pragma unroll
  for (int mi = 0; mi < 8; ++mi) {
    const int seq = seq0 + wm + mi * 16 + quad * 4;
    #pragma unroll
    for (int ni = 0; ni < 2; ++ni) {
      const int d = d0 + wn + ni * 16 + l16;
      union { ushort4 u; unsigned short sh[4]; } pk;
      #pragma unroll
      for (int r = 0; r < 4; ++r)
        pk.sh[r] = __bfloat16_as_ushort(__float2bfloat16(acc[mi][ni][r]));
      *(ushort4*)(Vt + ((long long)(b * 1024 + d)) * 2048 + seq) = pk.u;
    }
  }
}

// ---------------- S = exp(Q K^T) + row-sum partials, 256x256 ----------------
__global__ __launch_bounds__(512, 2)
void gemm_s_exp(const __hip_bfloat16* __restrict__ A,
                const __hip_bfloat16* __restrict__ B,
                __hip_bfloat16* __restrict__ Cout,
                float* __restrict__ part)
{
  __shared__ __align__(16) __hip_bfloat16 As[2][256 * 64];   // 64 KB
  __shared__ __align__(16) __hip_bfloat16 Bs[2][256 * 64];   // 64 KB

  // XCD swizzle: each XCD owns one batch-half: 4 tile_m x 8 tile_n.
  const int u   = blockIdx.x + (blockIdx.y << 3) + (blockIdx.z << 6);
  const int xcd = u & 7;
  const int rr  = u >> 3;                 // 0..31
  const int bz  = xcd >> 1;               // 2 XCDs per batch
  const int tmi = ((xcd & 1) << 2) + (rr >> 3);
  const int tni = rr & 7;

  A += (long long)bz * 2048 * 1024;
  B += (long long)bz * 2048 * 1024;

  const long long tile_m = (long long)tmi * 256;
  const long long tile_n = (long long)tni * 256;

  const int tid  = threadIdx.x;
  const int wid  = tid >> 6;
  const int lane = tid & 63;
  const int srow = wid * 8 + (lane >> 3);
  const int scol = ((lane & 7) ^ (lane >> 3)) * 8;

  const __hip_bfloat16* aS = A + (tile_m + srow) * 1024 + scol;
  const __hip_bfloat16* bS = B + (tile_n + srow) * 1024 + scol;

  const int wm   = (wid >> 2) * 128;
  const int wn   = (wid & 3) * 64;
  const int quad = lane >> 4;
  const int l16  = lane & 15;
  const int sw   = l16 & 7;

  f32x4 acc[8][4];
  #pragma unroll
  for (int mi = 0; mi < 8; ++mi)
    #pragma unroll
    for (int ni = 0; ni < 4; ++ni)
      acc[mi][ni] = (f32x4){0.f, 0.f, 0.f, 0.f};

  mainloop256<4, 16, 1024>(aS, bS, &As[0][0], &Bs[0][0],
                           wid, wm, wn, l16, quad, sw, acc);

  // epilogue: exp, bf16 store, per-wave 64-col row partials (32 per row total)
  __hip_bfloat16* C = Cout + (long long)bz * 2048 * 2048;
  #pragma unroll
  for (int mi = 0; mi < 8; ++mi) {
    #pragma unroll
    for (int r = 0; r < 4; ++r) {
      const long long row = tile_m + wm + mi * 16 + quad * 4 + r;
      float ssum = 0.f;
      #pragma unroll
      for (int ni = 0; ni < 4; ++ni) {
        const float e = __expf(acc[mi][ni][r]);
        const __hip_bfloat16 h = __float2bfloat16(e);
        C[row * 2048 + tile_n + wn + ni * 16 + l16] = h;
        ssum += __bfloat162float(h);
      }
      #pragma unroll
      for (int off = 1; off < 16; off <<= 1) ssum += __shfl_xor(ssum, off, 64);
      if (l16 == 0)
        part[((long long)bz * 2048 + row) * 32 + tni * 4 + (wid & 3)] = ssum;
    }
  }
}

// ---------------- O = (P Vt^T) / rowsum, 256x128, fence-free ----------------
__global__ __launch_bounds__(512, 2)
void gemm_pv(const __hip_bfloat16* __restrict__ A,     // expS [b][2048,2048]
             const __hip_bfloat16* __restrict__ B,     // Vt   [b][1024,2048]
             const float* __restrict__ part,           // [8192][32]
             float* __restrict__ Cout)                 // O    [b][2048,1024]
{
  __shared__ __align__(16) __hip_bfloat16 As[2][256 * 64];   // 64 KB
  __shared__ __align__(16) __hip_bfloat16 Bs[2][128 * 64];   // 32 KB
  __shared__ float rinv[256];

  // XCD swizzle: each XCD owns 4 tile_m x 8 tile_n of one batch.
  const int u   = blockIdx.x + (blockIdx.y << 3) + (blockIdx.z << 6);
  const int xcd = u & 7;
  const int rr  = u >> 3;
  const int bz  = xcd >> 1;
  const int tmi = ((xcd & 1) << 2) + (rr >> 3);
  const int tni = rr & 7;

  A += (long long)bz * 2048 * 2048;
  B += (long long)bz * 1024 * 2048;

  const long long tile_m = (long long)tmi * 256;
  const long long tile_n = (long long)tni * 128;

  const int tid  = threadIdx.x;
  const int wid  = tid >> 6;
  const int lane = tid & 63;
  const int srow = wid * 8 + (lane >> 3);
  const int scol = ((lane & 7) ^ (lane >> 3)) * 8;

  const __hip_bfloat16* aS = A + (tile_m + srow) * 2048 + scol;
  const __hip_bfloat16* bS = B + (tile_n + srow) * 2048 + scol;

  const int wm   = (wid >> 2) * 128;
  const int wn   = (wid & 3) * 32;
  const int quad = lane >> 4;
  const int l16  = lane & 15;
  const int sw   = l16 & 7;

  f32x4 acc[8][2];
  #pragma unroll
  for (int mi = 0; mi < 8; ++mi)
    #pragma unroll
    for (int ni = 0; ni < 2; ++ni)
      acc[mi][ni] = (f32x4){0.f, 0.f, 0.f, 0.f};

  mainloop128pf<32, 2048>(aS, bS, &As[0][0], &Bs[0][0],
                          wid, wm, wn, l16, quad, sw, acc);

  // gather this tile's 256 row-sums (32 partials each), store reciprocal
  if (tid < 256) {
    const float4* pp = (const float4*)(part + ((long long)bz * 2048 + tile_m + tid) * 32);
    float s = 0.f;
    #pragma unroll
    for (int j = 0; j < 8; ++j) {
      const float4 f = pp[j];
      s += f.x + f.y + f.z + f.w;
    }
    rinv[tid] = 1.f / s;
  }
  __syncthreads();

  float* C = Cout + (long long)bz * 2048 * 1024;
  #pragma unroll
  for (int mi = 0; mi < 8; ++mi) {
    #pragma unroll
    for (int r = 0; r < 4; ++r) {
      const int rloc = wm + mi * 16 + quad * 4 + r;
      const float inv = rinv[rloc];
      const long long row = tile_m + rloc;
      #pragma unroll
      for (int ni = 0; ni < 2; ++ni) {
        const long long col = tile_n + wn + ni * 16 + l16;
        C[row * 1024 + col] = acc[mi][ni][r] * inv;
      }
    }
  }
}

// ---------------- all casts in one dispatch ----------------
__global__ __launch_bounds__(256)
void cast_all(const float* __restrict__ x,
              const float* __restrict__ Wq, const float* __restrict__ Wk,
              const float* __restrict__ Wv,
              __hip_bfloat16* __restrict__ xb, __hip_bfloat16* __restrict__ wcat)
{
  const int bx = blockIdx.x;
  const float* src;
  __hip_bfloat16* dst;
  int i;
  if (bx < 8192) {                      // x: 2097152 float4s
    src = x; dst = xb; i = bx * 256 + threadIdx.x;
  } else {                              // weights: 262144 float4s each
    const int which = (bx - 8192) >> 10;
    src = (which == 0) ? Wq : (which == 1) ? Wk : Wv;
    dst = wcat + (long long)which * 1048576;
    i = ((bx - 8192) & 1023) * 256 + threadIdx.x;
  }
  const float4 f = ((const float4*)src)[i];
  union { ushort4 u; __hip_bfloat16 h[4]; } r;
  r.h[0] = __float2bfloat16(f.x);
  r.h[1] = __float2bfloat16(f.y);
  r.h[2] = __float2bfloat16(f.z);
  r.h[3] = __float2bfloat16(f.w);
  ((ushort4*)dst)[i] = r.u;
}

extern "C" void kernel_launch(void* const* d_in, const int* in_sizes, int n_in,
                              void* d_out, int out_size, void* d_ws, size_t ws_size,
                              hipStream_t stream)
{
  (void)in_sizes; (void)n_in; (void)out_size; (void)ws_size;

  const float* x  = (const float*)d_in[0];
  const float* Wq = (const float*)d_in[1];
  const float* Wk = (const float*)d_in[2];
  const float* Wv = (const float*)d_in[3];
  float* out = (float*)d_out;

  char* ws = (char*)d_ws;
  __hip_bfloat16* xb   = (__hip_bfloat16*)(ws);            // dead after gemm_v
  float*          part = (float*)(ws);                     // reuses xb region (1 MB)
  __hip_bfloat16* wcat = (__hip_bfloat16*)(ws + (16LL << 20));
  __hip_bfloat16* Q    = (__hip_bfloat16*)(ws + (22LL << 20));
  __hip_bfloat16* Kk   = (__hip_bfloat16*)(ws + (38LL << 20));
  __hip_bfloat16* Vt   = (__hip_bfloat16*)(ws + (54LL << 20));
  __hip_bfloat16* S    = (__hip_bfloat16*)(ws + (70LL << 20));

  cast_all<<<11264, 256, 0, stream>>>(x, Wq, Wk, Wv, xb, wcat);

  // Q,K projection: 32x8 tiles of 256^2 = 256 blocks (1 clean round)
  gemm_qk<<<256, 512, 0, stream>>>(xb, wcat, Q, Kk);

  // V projection: 32x8 tiles of 256x128 = 256 blocks; V lands transposed
  gemm_v<<<256, 512, 0, stream>>>(xb, wcat + 2097152, Vt);

  // S = exp(Q K^T), row-sum partials -> part (overwrites dead xb)
  gemm_s_exp<<<dim3(8, 8, 4), 512, 0, stream>>>(Q, Kk, S, part);

  // O = (P Vt^T) / rowsum -> fp32 d_out
  gemm_pv<<<dim3(8, 8, 4), 512, 0, stream>>>(S, Vt, part, out);
}

// Round 12
// 223.559 us; speedup vs baseline: 1.0118x; 1.0093x over previous
//
#include <hip/hip_runtime.h>
#include <hip/hip_bf16.h>
#include <stdint.h>

// ---------------------------------------------------------------------------
// Self-attention, single head, d=1024, seq=2048, batch=4, fp32 in/out.
// R19: revert R18 (fence-free regressed 43.4->49.2; R17 triple-buf also
//      regressed). R16 = verified best (220.9 us). This round: TRAFFIC, not
//      order. gemm_v/gemm_pv wave grid reshaped 2x4 (128x32 waves) ->
//      4x2 (64x64 waves): per-CU LDS fragment reads per K-tile drop
//      8*(128+32)*64*2B=160KB -> 8*(64+64)*64*2B=128KB (-20%), MFMA count
//      unchanged (32/wave/tile). mainloopW64 keeps R16's verified skeleton
//      exactly (double buffer, stage t+1 per tile, pinned vmcnt(0) gate,
//      one barrier, setprio-bracketed 16-MFMA clusters); only the fragment
//      map changes: afc = rows 0-31, afn = rows 32-63, bfr = 4 n-frags.
//      qk/sexp byte-identical R16 (control).
//      Hazards (== R16, audited): stage(t+1)->buf^1 last read before
//      t-1's end barrier; per-wave gate precedes end barrier; afc/afn/bfr
//      written once per tile before consumption.
// Pipeline: cast_all | QK proj | V proj (-> Vt scatter) |
//           S = exp(QK^T) + rowsum partials | O = (P Vt^T)/rowsum
// Workspace (102 MiB): xb @ 0 (16; 1st MiB reused as part after v)
//   wcat @ 16 (6)  Q @ 22 (16)  K @ 38 (16)  Vt @ 54 (16)  S @ 70 (32)
// ---------------------------------------------------------------------------

typedef __attribute__((ext_vector_type(8))) short bf16x8;   // 8 bf16 = 4 VGPRs
typedef __attribute__((ext_vector_type(4))) float f32x4;

__device__ __forceinline__ void async_copy16(const void* g, void* l) {
  __builtin_amdgcn_global_load_lds(
      (__attribute__((address_space(1))) void*)(g),
      (__attribute__((address_space(3))) void*)(l),
      16, 0, 0);
}

#define SB0 __builtin_amdgcn_sched_barrier(0)

// ---- 256xBN / BK=64 / 1-barrier-per-tile double-buffered mainloop ----
// (R16 verified; used by qk/sexp with NI=4.)
template<int NI, int NT, int KS>
__device__ __forceinline__ void mainloop256(
    const __hip_bfloat16* __restrict__ aS,
    const __hip_bfloat16* __restrict__ bS,
    __hip_bfloat16* As, __hip_bfloat16* Bs,
    const int wid, const int wm, const int wn,
    const int l16, const int quad, const int sw,
    f32x4 (&acc)[8][NI])
{
  const bf16x8* Av = (const bf16x8*)As;
  const bf16x8* Bv = (const bf16x8*)Bs;
  char* lA = (char*)As + wid * 1024;     // wave-uniform stage base
  char* lB = (char*)Bs + wid * 1024;
  bf16x8 bfr[NI][2];
  bf16x8 afc[2][2], afn[2][2];

#define STG_A2(t) do { \
    _Pragma("unroll") \
    for (int p = 0; p < 4; ++p) \
      async_copy16(aS + ((t)*64 + (long long)p * 64 * KS), \
                   lA + ((t)&1)*32768 + p * 64 * 128); \
  } while (0)
#define STG_B2(t) do { \
    _Pragma("unroll") \
    for (int p = 0; p < NI; ++p) \
      async_copy16(bS + ((t)*64 + (long long)p * 64 * KS), \
                   lB + ((t)&1)*(NI*8192) + p * 64 * 128); \
  } while (0)
#define RD_AF(dst, t, phi) do { \
    _Pragma("unroll") \
    for (int m2 = 0; m2 < 2; ++m2) \
      _Pragma("unroll") \
      for (int kk = 0; kk < 2; ++kk) \
        dst[m2][kk] = Av[((t)&1)*2048 + (wm + ((phi)*2 + m2)*16 + l16)*8 + ((kk*4 + quad) ^ sw)]; \
  } while (0)
#define RD_BF(t, nlo, nhi) do { \
    _Pragma("unroll") \
    for (int ni = (nlo); ni < (nhi); ++ni) \
      _Pragma("unroll") \
      for (int kk = 0; kk < 2; ++kk) \
        bfr[ni][kk] = Bv[((t)&1)*(NI*512) + (wn + ni*16 + l16)*8 + ((kk*4 + quad) ^ sw)]; \
  } while (0)
#define MM(src, phi, nlo, nhi) do { \
    _Pragma("unroll") \
    for (int kk = 0; kk < 2; ++kk) \
      _Pragma("unroll") \
      for (int m2 = 0; m2 < 2; ++m2) \
        _Pragma("unroll") \
        for (int ni = (nlo); ni < (nhi); ++ni) \
          acc[(phi)*2 + m2][ni] = __builtin_amdgcn_mfma_f32_16x16x32_bf16( \
              src[m2][kk], bfr[ni][kk], acc[(phi)*2 + m2][ni], 0, 0, 0); \
  } while (0)
#define GATE0 do { SB0; \
    asm volatile("s_waitcnt vmcnt(0)" ::: "memory"); } while (0)
#define GNONE (void)0

#define TILE(t, STG_STMT, GATE_STMT) do { \
    RD_BF(t, 0, NI); \
    RD_AF(afc, t, 0); \
    RD_AF(afn, t, 1); \
    STG_STMT; \
    __builtin_amdgcn_s_setprio(1); MM(afc, 0, 0, NI); __builtin_amdgcn_s_setprio(0); \
    RD_AF(afc, t, 2); \
    __builtin_amdgcn_s_setprio(1); \
    MM(afn, 1, 0, NI); \
    __builtin_amdgcn_s_setprio(0); \
    RD_AF(afn, t, 3); \
    __builtin_amdgcn_s_setprio(1); \
    MM(afc, 2, 0, NI); \
    MM(afn, 3, 0, NI); \
    __builtin_amdgcn_s_setprio(0); \
    GATE_STMT; \
    SB0; \
    __builtin_amdgcn_s_barrier(); \
  } while (0)

  STG_B2(0); STG_A2(0);
  GATE0;
  __builtin_amdgcn_s_barrier();

  #pragma unroll 1
  for (int i = 0; i < NT / 2 - 1; ++i) {
    const int ta = 2 * i, tb = 2 * i + 1;
    TILE(ta, { STG_A2(ta + 1); STG_B2(ta + 1); }, GATE0);
    TILE(tb, { STG_A2(tb + 1); STG_B2(tb + 1); }, GATE0);
  }
  TILE(NT - 2, { STG_A2(NT - 1); STG_B2(NT - 1); }, GATE0);
  TILE(NT - 1, GNONE, GNONE);

#undef TILE
#undef GATE0
#undef GNONE
#undef MM
#undef RD_BF
#undef RD_AF
#undef STG_A2
#undef STG_B2
}

// ---- 256x128 / BK=64 / 64x64-wave mainloop (R16 skeleton) ----
// 8 waves as 4x2: wm = (wid>>1)*64, wn = (wid&1)*64. acc[4][4].
// Per wave per tile: 8 A-reads + 8 B-reads (128KB/CU, was 160), 32 MFMA.
// As: LDS [2][256*64] (64KB). Bs: LDS [2][128*64] (32KB).
template<int NT, int KS>
__device__ __forceinline__ void mainloopW64(
    const __hip_bfloat16* __restrict__ aS,
    const __hip_bfloat16* __restrict__ bS,
    __hip_bfloat16* As, __hip_bfloat16* Bs,
    const int wid, const int wm, const int wn,
    const int l16, const int quad, const int sw,
    f32x4 (&acc)[4][4])
{
  const bf16x8* Av = (const bf16x8*)As;
  const bf16x8* Bv = (const bf16x8*)Bs;
  char* lA = (char*)As + wid * 1024;
  char* lB = (char*)Bs + wid * 1024;
  bf16x8 bfr[4][2];
  bf16x8 afc[2][2], afn[2][2];   // afc: rows wm+0..31, afn: rows wm+32..63

#define WSTG_A(t) do { \
    _Pragma("unroll") \
    for (int p = 0; p < 4; ++p) \
      async_copy16(aS + ((t)*64 + (long long)p * 64 * KS), \
                   lA + ((t)&1)*32768 + p * 64 * 128); \
  } while (0)
#define WSTG_B(t) do { \
    _Pragma("unroll") \
    for (int p = 0; p < 2; ++p) \
      async_copy16(bS + ((t)*64 + (long long)p * 64 * KS), \
                   lB + ((t)&1)*16384 + p * 64 * 128); \
  } while (0)
#define WRD_AF(dst, t, half) do { \
    _Pragma("unroll") \
    for (int m2 = 0; m2 < 2; ++m2) \
      _Pragma("unroll") \
      for (int kk = 0; kk < 2; ++kk) \
        dst[m2][kk] = Av[((t)&1)*2048 + (wm + ((half)*2 + m2)*16 + l16)*8 + ((kk*4 + quad) ^ sw)]; \
  } while (0)
#define WRD_BF(t) do { \
    _Pragma("unroll") \
    for (int ni = 0; ni < 4; ++ni) \
      _Pragma("unroll") \
      for (int kk = 0; kk < 2; ++kk) \
        bfr[ni][kk] = Bv[((t)&1)*1024 + (wn + ni*16 + l16)*8 + ((kk*4 + quad) ^ sw)]; \
  } while (0)
#define WMM(src, half) do { \
    _Pragma("unroll") \
    for (int kk = 0; kk < 2; ++kk) \
      _Pragma("unroll") \
      for (int m2 = 0; m2 < 2; ++m2) \
        _Pragma("unroll") \
        for (int ni = 0; ni < 4; ++ni) \
          acc[(half)*2 + m2][ni] = __builtin_amdgcn_mfma_f32_16x16x32_bf16( \
              src[m2][kk], bfr[ni][kk], acc[(half)*2 + m2][ni], 0, 0, 0); \
  } while (0)
#define WGATE0 do { SB0; \
    asm volatile("s_waitcnt vmcnt(0)" ::: "memory"); } while (0)
#define WGNONE (void)0

#define WTILE(t, STG_STMT, GATE_STMT) do { \
    WRD_BF(t); \
    WRD_AF(afc, t, 0); \
    WRD_AF(afn, t, 1); \
    STG_STMT; \
    __builtin_amdgcn_s_setprio(1); WMM(afc, 0); __builtin_amdgcn_s_setprio(0); \
    __builtin_amdgcn_s_setprio(1); WMM(afn, 1); __builtin_amdgcn_s_setprio(0); \
    GATE_STMT; \
    SB0; \
    __builtin_amdgcn_s_barrier(); \
  } while (0)

  WSTG_B(0); WSTG_A(0);
  WGATE0;
  __builtin_amdgcn_s_barrier();

  #pragma unroll 1
  for (int i = 0; i < NT / 2 - 1; ++i) {
    const int ta = 2 * i, tb = 2 * i + 1;
    WTILE(ta, { WSTG_A(ta + 1); WSTG_B(ta + 1); }, WGATE0);
    WTILE(tb, { WSTG_A(tb + 1); WSTG_B(tb + 1); }, WGATE0);
  }
  WTILE(NT - 2, { WSTG_A(NT - 1); WSTG_B(NT - 1); }, WGATE0);
  WTILE(NT - 1, WGNONE, WGNONE);

#undef WTILE
#undef WGATE0
#undef WGNONE
#undef WMM
#undef WRD_BF
#undef WRD_AF
#undef WSTG_A
#undef WSTG_B
}

// ---------------- Q,K projection, 256x256, grid 256 ----------------
// A = xb [8192,1024], B = wcat rows 0..2047 (Wq | Wk)
__global__ __launch_bounds__(512, 2)
void gemm_qk(const __hip_bfloat16* __restrict__ A,
             const __hip_bfloat16* __restrict__ B,
             __hip_bfloat16* __restrict__ Q,
             __hip_bfloat16* __restrict__ Kk)
{
  __shared__ __align__(16) __hip_bfloat16 As[2][256 * 64];   // 64 KB
  __shared__ __align__(16) __hip_bfloat16 Bs[2][256 * 64];   // 64 KB

  // XCD-chunked bijective swizzle: 256 = 8 XCD * 32.
  const int bid = blockIdx.x;
  const int s   = (bid & 7) * 32 + (bid >> 3);
  const long long tile_m = (long long)(s >> 3) * 256;
  const long long tile_n = (long long)(s & 7) * 256;

  const int tid  = threadIdx.x;
  const int wid  = tid >> 6;
  const int lane = tid & 63;
  const int srow = wid * 8 + (lane >> 3);
  const int scol = ((lane & 7) ^ (lane >> 3)) * 8;   // swizzled source chunk

  const __hip_bfloat16* aS = A + (tile_m + srow) * 1024 + scol;
  const __hip_bfloat16* bS = B + (tile_n + srow) * 1024 + scol;

  const int wm   = (wid >> 2) * 128;
  const int wn   = (wid & 3) * 64;
  const int quad = lane >> 4;
  const int l16  = lane & 15;
  const int sw   = l16 & 7;

  f32x4 acc[8][4];
  #pragma unroll
  for (int mi = 0; mi < 8; ++mi)
    #pragma unroll
    for (int ni = 0; ni < 4; ++ni)
      acc[mi][ni] = (f32x4){0.f, 0.f, 0.f, 0.f};

  mainloop256<4, 16, 1024>(aS, bS, &As[0][0], &Bs[0][0],
                           wid, wm, wn, l16, quad, sw, acc);

  // C/D layout (m89/m91): col = l16, row = quad*4 + r
  const int mat = (int)(tile_n >> 10);
  __hip_bfloat16* outp = (mat == 0) ? Q : Kk;
  const float scale = (mat == 0) ? 0.03125f : 1.0f;   // 1/sqrt(1024) in Q
  const int coln0 = (int)(tile_n & 1023);
  #pragma unroll
  for (int mi = 0; mi < 8; ++mi) {
    #pragma unroll
    for (int r = 0; r < 4; ++r) {
      const long long row = tile_m + wm + mi * 16 + quad * 4 + r;
      #pragma unroll
      for (int ni = 0; ni < 4; ++ni) {
        const int col = coln0 + wn + ni * 16 + l16;
        outp[row * 1024 + col] = __float2bfloat16(acc[mi][ni][r] * scale);
      }
    }
  }
}

// ---------------- V projection, 256x128, grid 256, 64x64 waves ----------------
// A = xb [8192,1024], B = Wv rows.  V -> Vt [4][1024][2048] via 8B scatter.
__global__ __launch_bounds__(512, 2)
void gemm_v(const __hip_bfloat16* __restrict__ A,
            const __hip_bfloat16* __restrict__ B,
            __hip_bfloat16* __restrict__ Vt)
{
  __shared__ __align__(16) __hip_bfloat16 As[2][256 * 64];   // 64 KB
  __shared__ __align__(16) __hip_bfloat16 Bs[2][128 * 64];   // 32 KB

  const int bid = blockIdx.x;
  const int s   = (bid & 7) * 32 + (bid >> 3);
  const long long tile_m = (long long)(s >> 3) * 256;
  const long long tile_n = (long long)(s & 7) * 128;

  const int tid  = threadIdx.x;
  const int wid  = tid >> 6;
  const int lane = tid & 63;
  const int srow = wid * 8 + (lane >> 3);
  const int scol = ((lane & 7) ^ (lane >> 3)) * 8;

  const __hip_bfloat16* aS = A + (tile_m + srow) * 1024 + scol;
  const __hip_bfloat16* bS = B + (tile_n + srow) * 1024 + scol;

  const int wm   = (wid >> 1) * 64;      // 4x2 wave grid, 64x64 tiles
  const int wn   = (wid & 1) * 64;
  const int quad = lane >> 4;
  const int l16  = lane & 15;
  const int sw   = l16 & 7;

  f32x4 acc[4][4];
  #pragma unroll
  for (int mi = 0; mi < 4; ++mi)
    #pragma unroll
    for (int ni = 0; ni < 4; ++ni)
      acc[mi][ni] = (f32x4){0.f, 0.f, 0.f, 0.f};

  mainloopW64<16, 1024>(aS, bS, &As[0][0], &Bs[0][0],
                        wid, wm, wn, l16, quad, sw, acc);

  // V: lane's 4 r-values are seq-consecutive -> one 8B store per (mi,ni).
  const int b    = (int)(tile_m >> 11);
  const int seq0 = (int)(tile_m & 2047);
  const int d0   = (int)tile_n;
  #pragma unroll
  for (int mi = 0; mi < 4; ++mi) {
    const int seq = seq0 + wm + mi * 16 + quad * 4;
    #pragma unroll
    for (int ni = 0; ni < 4; ++ni) {
      const int d = d0 + wn + ni * 16 + l16;
      union { ushort4 u; unsigned short sh[4]; } pk;
      #pragma unroll
      for (int r = 0; r < 4; ++r)
        pk.sh[r] = __bfloat16_as_ushort(__float2bfloat16(acc[mi][ni][r]));
      *(ushort4*)(Vt + ((long long)(b * 1024 + d)) * 2048 + seq) = pk.u;
    }
  }
}

// ---------------- S = exp(Q K^T) + row-sum partials, 256x256 ----------------
__global__ __launch_bounds__(512, 2)
void gemm_s_exp(const __hip_bfloat16* __restrict__ A,
                const __hip_bfloat16* __restrict__ B,
                __hip_bfloat16* __restrict__ Cout,
                float* __restrict__ part)
{
  __shared__ __align__(16) __hip_bfloat16 As[2][256 * 64];   // 64 KB
  __shared__ __align__(16) __hip_bfloat16 Bs[2][256 * 64];   // 64 KB

  // XCD swizzle: each XCD owns one batch-half: 4 tile_m x 8 tile_n.
  const int u   = blockIdx.x + (blockIdx.y << 3) + (blockIdx.z << 6);
  const int xcd = u & 7;
  const int rr  = u >> 3;                 // 0..31
  const int bz  = xcd >> 1;               // 2 XCDs per batch
  const int tmi = ((xcd & 1) << 2) + (rr >> 3);
  const int tni = rr & 7;

  A += (long long)bz * 2048 * 1024;
  B += (long long)bz * 2048 * 1024;

  const long long tile_m = (long long)tmi * 256;
  const long long tile_n = (long long)tni * 256;

  const int tid  = threadIdx.x;
  const int wid  = tid >> 6;
  const int lane = tid & 63;
  const int srow = wid * 8 + (lane >> 3);
  const int scol = ((lane & 7) ^ (lane >> 3)) * 8;

  const __hip_bfloat16* aS = A + (tile_m + srow) * 1024 + scol;
  const __hip_bfloat16* bS = B + (tile_n + srow) * 1024 + scol;

  const int wm   = (wid >> 2) * 128;
  const int wn   = (wid & 3) * 64;
  const int quad = lane >> 4;
  const int l16  = lane & 15;
  const int sw   = l16 & 7;

  f32x4 acc[8][4];
  #pragma unroll
  for (int mi = 0; mi < 8; ++mi)
    #pragma unroll
    for (int ni = 0; ni < 4; ++ni)
      acc[mi][ni] = (f32x4){0.f, 0.f, 0.f, 0.f};

  mainloop256<4, 16, 1024>(aS, bS, &As[0][0], &Bs[0][0],
                           wid, wm, wn, l16, quad, sw, acc);

  // epilogue: exp, bf16 store, per-wave 64-col row partials (32 per row total)
  __hip_bfloat16* C = Cout + (long long)bz * 2048 * 2048;
  #pragma unroll
  for (int mi = 0; mi < 8; ++mi) {
    #pragma unroll
    for (int r = 0; r < 4; ++r) {
      const long long row = tile_m + wm + mi * 16 + quad * 4 + r;
      float ssum = 0.f;
      #pragma unroll
      for (int ni = 0; ni < 4; ++ni) {
        const float e = __expf(acc[mi][ni][r]);
        const __hip_bfloat16 h = __float2bfloat16(e);
        C[row * 2048 + tile_n + wn + ni * 16 + l16] = h;
        ssum += __bfloat162float(h);
      }
      #pragma unroll
      for (int off = 1; off < 16; off <<= 1) ssum += __shfl_xor(ssum, off, 64);
      if (l16 == 0)
        part[((long long)bz * 2048 + row) * 32 + tni * 4 + (wid & 3)] = ssum;
    }
  }
}

// ---------------- O = (P Vt^T) / rowsum, 256x128, 64x64 waves ----------------
__global__ __launch_bounds__(512, 2)
void gemm_pv(const __hip_bfloat16* __restrict__ A,     // expS [b][2048,2048]
             const __hip_bfloat16* __restrict__ B,     // Vt   [b][1024,2048]
             const float* __restrict__ part,           // [8192][32]
             float* __restrict__ Cout)                 // O    [b][2048,1024]
{
  __shared__ __align__(16) __hip_bfloat16 As[2][256 * 64];   // 64 KB
  __shared__ __align__(16) __hip_bfloat16 Bs[2][128 * 64];   // 32 KB
  __shared__ float rinv[256];

  // XCD swizzle: each XCD owns 4 tile_m x 8 tile_n of one batch.
  const int u   = blockIdx.x + (blockIdx.y << 3) + (blockIdx.z << 6);
  const int xcd = u & 7;
  const int rr  = u >> 3;
  const int bz  = xcd >> 1;
  const int tmi = ((xcd & 1) << 2) + (rr >> 3);
  const int tni = rr & 7;

  A += (long long)bz * 2048 * 2048;
  B += (long long)bz * 1024 * 2048;

  const long long tile_m = (long long)tmi * 256;
  const long long tile_n = (long long)tni * 128;

  const int tid  = threadIdx.x;
  const int wid  = tid >> 6;
  const int lane = tid & 63;
  const int srow = wid * 8 + (lane >> 3);
  const int scol = ((lane & 7) ^ (lane >> 3)) * 8;

  const __hip_bfloat16* aS = A + (tile_m + srow) * 2048 + scol;
  const __hip_bfloat16* bS = B + (tile_n + srow) * 2048 + scol;

  const int wm   = (wid >> 1) * 64;      // 4x2 wave grid, 64x64 tiles
  const int wn   = (wid & 1) * 64;
  const int quad = lane >> 4;
  const int l16  = lane & 15;
  const int sw   = l16 & 7;

  f32x4 acc[4][4];
  #pragma unroll
  for (int mi = 0; mi < 4; ++mi)
    #pragma unroll
    for (int ni = 0; ni < 4; ++ni)
      acc[mi][ni] = (f32x4){0.f, 0.f, 0.f, 0.f};

  mainloopW64<32, 2048>(aS, bS, &As[0][0], &Bs[0][0],
                        wid, wm, wn, l16, quad, sw, acc);

  // gather this tile's 256 row-sums (32 partials each), store reciprocal
  if (tid < 256) {
    const float4* pp = (const float4*)(part + ((long long)bz * 2048 + tile_m + tid) * 32);
    float s = 0.f;
    #pragma unroll
    for (int j = 0; j < 8; ++j) {
      const float4 f = pp[j];
      s += f.x + f.y + f.z + f.w;
    }
    rinv[tid] = 1.f / s;
  }
  __syncthreads();

  float* C = Cout + (long long)bz * 2048 * 1024;
  #pragma unroll
  for (int mi = 0; mi < 4; ++mi) {
    #pragma unroll
    for (int r = 0; r < 4; ++r) {
      const int rloc = wm + mi * 16 + quad * 4 + r;
      const float inv = rinv[rloc];
      const long long row = tile_m + rloc;
      #pragma unroll
      for (int ni = 0; ni < 4; ++ni) {
        const long long col = tile_n + wn + ni * 16 + l16;
        C[row * 1024 + col] = acc[mi][ni][r] * inv;
      }
    }
  }
}

// ---------------- all casts in one dispatch ----------------
__global__ __launch_bounds__(256)
void cast_all(const float* __restrict__ x,
              const float* __restrict__ Wq, const float* __restrict__ Wk,
              const float* __restrict__ Wv,
              __hip_bfloat16* __restrict__ xb, __hip_bfloat16* __restrict__ wcat)
{
  const int bx = blockIdx.x;
  const float* src;
  __hip_bfloat16* dst;
  int i;
  if (bx < 8192) {                      // x: 2097152 float4s
    src = x; dst = xb; i = bx * 256 + threadIdx.x;
  } else {                              // weights: 262144 float4s each
    const int which = (bx - 8192) >> 10;
    src = (which == 0) ? Wq : (which == 1) ? Wk : Wv;
    dst = wcat + (long long)which * 1048576;
    i = ((bx - 8192) & 1023) * 256 + threadIdx.x;
  }
  const float4 f = ((const float4*)src)[i];
  union { ushort4 u; __hip_bfloat16 h[4]; } r;
  r.h[0] = __float2bfloat16(f.x);
  r.h[1] = __float2bfloat16(f.y);
  r.h[2] = __float2bfloat16(f.z);
  r.h[3] = __float2bfloat16(f.w);
  ((ushort4*)dst)[i] = r.u;
}

extern "C" void kernel_launch(void* const* d_in, const int* in_sizes, int n_in,
                              void* d_out, int out_size, void* d_ws, size_t ws_size,
                              hipStream_t stream)
{
  (void)in_sizes; (void)n_in; (void)out_size; (void)ws_size;

  const float* x  = (const float*)d_in[0];
  const float* Wq = (const float*)d_in[1];
  const float* Wk = (const float*)d_in[2];
  const float* Wv = (const float*)d_in[3];
  float* out = (float*)d_out;

  char* ws = (char*)d_ws;
  __hip_bfloat16* xb   = (__hip_bfloat16*)(ws);            // dead after gemm_v
  float*          part = (float*)(ws);                     // reuses xb region (1 MB)
  __hip_bfloat16* wcat = (__hip_bfloat16*)(ws + (16LL << 20));
  __hip_bfloat16* Q    = (__hip_bfloat16*)(ws + (22LL << 20));
  __hip_bfloat16* Kk   = (__hip_bfloat16*)(ws + (38LL << 20));
  __hip_bfloat16* Vt   = (__hip_bfloat16*)(ws + (54LL << 20));
  __hip_bfloat16* S    = (__hip_bfloat16*)(ws + (70LL << 20));

  cast_all<<<11264, 256, 0, stream>>>(x, Wq, Wk, Wv, xb, wcat);

  // Q,K projection: 32x8 tiles of 256^2 = 256 blocks (1 clean round)
  gemm_qk<<<256, 512, 0, stream>>>(xb, wcat, Q, Kk);

  // V projection: 32x8 tiles of 256x128 = 256 blocks; V lands transposed
  gemm_v<<<256, 512, 0, stream>>>(xb, wcat + 2097152, Vt);

  // S = exp(Q K^T), row-sum partials -> part (overwrites dead xb)
  gemm_s_exp<<<dim3(8, 8, 4), 512, 0, stream>>>(Q, Kk, S, part);

  // O = (P Vt^T) / rowsum -> fp32 d_out
  gemm_pv<<<dim3(8, 8, 4), 512, 0, stream>>>(S, Vt, part, out);
}